// Round 13
// baseline (134.416 us; speedup 1.0000x reference)
//
#include <hip/hip_runtime.h>
#include <hip/hip_bf16.h>
#include <math.h>

#define LTOT 36864      // 192*192
#define NH 4
#define NCHUNK 256
#define CHU 144
#define NBUCK 128
#define NSEG 144        // 36864 / 256
#define HW_ 192
#define VTS 148         // VT row stride (u16)

typedef unsigned int u32;
typedef unsigned short u16;
typedef unsigned long long u64;
typedef __attribute__((ext_vector_type(4))) short short4v;
typedef __attribute__((ext_vector_type(4))) float f32x4;

__device__ __forceinline__ u32 pkbf(float a, float b){
  union { __hip_bfloat162 h2; u32 u; } cv;
  cv.h2 = __float22bfloat162_rn(float2{a,b});
  return cv.u;
}
__device__ __forceinline__ float bflo(u32 w){ return __uint_as_float(w<<16); }
__device__ __forceinline__ float bfhi(u32 w){ return __uint_as_float(w & 0xffff0000u); }

// ---------------- conv + hash + histogram fused: 576 blocks x 512 threads (8 waves) ----------------
// Wave w (0..7): one 3x3 co (=w) + four 1x1 co (4w..4w+3) for its 64 px.
// Phase B (waves 0..3): hash, px=lane, h=wave (rot reads wave-uniform -> s_load).
__global__ __launch_bounds__(512) void k_conv(const float* __restrict__ x,
    const float* __restrict__ wm, const float* __restrict__ bm,
    const float* __restrict__ wa, const float* __restrict__ ba,
    const float* __restrict__ rot,
    float* __restrict__ xe, u16* __restrict__ Vu, int* __restrict__ code,
    int* __restrict__ hist)
{
  __shared__ float xs[32*108];   // 32 ci x 6x18 halo
  __shared__ float xq[64*8];     // this tile's xe rows
  const int t = threadIdx.x;
  const int id = blockIdx.x;
  const int bx = id % 12, by = id / 12;

  for (int idx=t; idx<3456; idx+=512){
    int ci = idx/108, rem = idx-ci*108;
    int iy = rem/18,  ix = rem-iy*18;
    int yy = by*4+iy-1, xx = bx*16+ix-1;
    float v = 0.f;
    if (yy>=0 && yy<HW_ && xx>=0 && xx<HW_) v = x[ci*LTOT + yy*HW_ + xx];
    xs[idx] = v;
  }
  __syncthreads();
  const int lane = t & 63;
  const int w  = __builtin_amdgcn_readfirstlane(t>>6);   // 0..7
  const int co = w;        // 3x3 out channel
  const int cb = 4*w;      // 1x1 out channels cb..cb+3
  const int ix = lane & 15, iy = lane >> 4;
  float a0 = bm[co];
  float acc[4];
  #pragma unroll
  for (int j=0;j<4;j++) acc[j] = ba[cb+j];
  const float* xb  = xs + iy*18 + ix;
  const float* w0p = wm + co*288;
  for (int ci=0; ci<32; ci++){
    const float* xp = xb + ci*108;
    float x00=xp[0],  x01=xp[1],  x02=xp[2];
    float x10=xp[18], x11=xp[19], x12=xp[20];
    float x20=xp[36], x21=xp[37], x22=xp[38];
    const float* w0 = w0p + ci*9;
    a0 += x00*w0[0]+x01*w0[1]+x02*w0[2]
        + x10*w0[3]+x11*w0[4]+x12*w0[5]
        + x20*w0[6]+x21*w0[7]+x22*w0[8];
    const float* wap = wa + cb*32 + ci;
    #pragma unroll
    for (int j=0;j<4;j++) acc[j] += x11 * wap[j*32];
  }
  const int l = (by*4+iy)*HW_ + bx*16+ix;
  xe[l*8 + co] = a0;
  xq[lane*8 + co] = a0;
  uint2 vv;
  vv.x = pkbf(acc[0],acc[1]); vv.y = pkbf(acc[2],acc[3]);
  *(uint2*)(Vu + (size_t)l*32 + cb) = vv;
  __syncthreads();

  // phase B: hash (waves 0..3): px = lane, h = wave id
  if (t < 256){
    const int h = w;
    const float4* qp = (const float4*)(xq + lane*8);
    float4 qa = qp[0], qb = qp[1];
    float best = -INFINITY; int bi = 0;
    float worst = INFINITY; int wi = 0;
    for (int i=0; i<64; i++){
      const float* rp = rot + h*64 + i;   // rot[f*256 + h*64 + i]
      float v = qa.x*rp[0]    + qa.y*rp[256]  + qa.z*rp[512]  + qa.w*rp[768]
              + qb.x*rp[1024] + qb.y*rp[1280] + qb.z*rp[1536] + qb.w*rp[1792];
      if (v > best)  { best  = v; bi = i; }
      if (v < worst) { worst = v; wi = i; }
    }
    int c = (-worst > best) ? (64+wi) : bi;
    const int ly = lane >> 4, lx = lane & 15;
    const int lpix = (by*4+ly)*HW_ + bx*16+lx;
    code[h*LTOT + lpix] = c;
    atomicAdd(&hist[(h*NSEG + (lpix>>8))*NBUCK + c], 1);
  }
}

// ---------------- scatter: per-block scan (from hist) + ballot rank + materialize ----------------
__global__ __launch_bounds__(256) void k_scatter(const int* __restrict__ code,
    const int* __restrict__ hist,
    const float* __restrict__ xe, const u16* __restrict__ Vu,
    int* __restrict__ spos, u16* __restrict__ Ks, u16* __restrict__ Qs,
    u16* __restrict__ Vs)
{
  const int h = blockIdx.y, seg = blockIdx.x, t = threadIdx.x;
  const int l = seg*256 + t;
  int c = code[h*LTOT + l];

  __shared__ int pre2[2][NBUCK], tot2[2][NBUCK];
  __shared__ int scv[NBUCK];
  __shared__ int segbase[NBUCK];
  __shared__ int wh[4][NBUCK];

  {
    const int b = t & 127, gg = t >> 7;
    int pre = 0, tt = 0;
    const int sA = gg*72;
    for (int s = sA; s < sA+72; s++){
      int v = hist[(h*NSEG+s)*NBUCK + b];
      tt += v;
      if (s < seg) pre += v;
    }
    pre2[gg][b] = pre; tot2[gg][b] = tt;
  }
  const int lane = t & 63, w = t >> 6;
  u64 mask = ~0ull;
  #pragma unroll
  for (int bit=0; bit<7; bit++){
    u64 bset = __ballot((c>>bit)&1);
    mask &= ((c>>bit)&1) ? bset : ~bset;
  }
  int rin = __popcll(mask & ((lane==0)?0ull:(~0ull >> (64-lane))));
  int cnt = __popcll(mask);
  ((int*)wh)[t] = 0; ((int*)wh)[t+256] = 0;
  __syncthreads();

  if (rin == 0) wh[w][c] = cnt;
  if (t < NBUCK){
    int tt = tot2[0][t] + tot2[1][t];
    int v = tt;
    #pragma unroll
    for (int off=1; off<64; off<<=1){
      int u = __shfl_up(v, off);
      if ((t & 63) >= off) v += u;
    }
    scv[t] = v;
  }
  __syncthreads();

  if (t < NBUCK){
    int tt = tot2[0][t] + tot2[1][t];
    int excl = scv[t] - tt + ((t >= 64) ? scv[63] : 0);
    segbase[t] = excl + pre2[0][t] + pre2[1][t];
  }
  __syncthreads();

  int r = segbase[c] + rin;
  for (int ww=0; ww<w; ww++) r += wh[ww][c];
  spos[h*LTOT + r] = l;

  const float4* xr = (const float4*)(xe + l*8);
  float4 a = xr[0], b = xr[1];
  float n2 = a.x*a.x+a.y*a.y+a.z*a.z+a.w*a.w
           + b.x*b.x+b.y*b.y+b.z*b.z+b.w*b.w;
  float sc = 1.0f / fmaxf(sqrtf(n2), 5e-5f);
  uint4 kk, qq;
  kk.x = pkbf(a.x*sc,a.y*sc); kk.y = pkbf(a.z*sc,a.w*sc);
  kk.z = pkbf(b.x*sc,b.y*sc); kk.w = pkbf(b.z*sc,b.w*sc);
  qq.x = pkbf(a.x,a.y); qq.y = pkbf(a.z,a.w);
  qq.z = pkbf(b.x,b.y); qq.w = pkbf(b.z,b.w);
  *(uint4*)(Ks + (size_t)(h*LTOT + r)*8) = kk;
  *(uint4*)(Qs + (size_t)(h*LTOT + r)*8) = qq;

  const uint4* vr = (const uint4*)(Vu + (size_t)l*32);
  uint4* vp = (uint4*)(Vs + (size_t)(h*LTOT + r)*32);
  vp[0] = vr[0]; vp[1] = vr[1]; vp[2] = vr[2]; vp[3] = vr[3];
}

// ---------------- chunked attention: ALL staging up-front, 27 straight MFMA tiles;
//                  outputs scattered directly to unsorted order ----------------
__global__ __launch_bounds__(320) void k_attn(const u16* __restrict__ Ks,
    const u16* __restrict__ Qs, const u16* __restrict__ Vs,
    const int* __restrict__ spos, u16* __restrict__ ret_u, float* __restrict__ bs_u)
{
  __shared__ __align__(16) u16 Klds[432*8];
  __shared__ __align__(16) u16 Qlds[CHU*8];
  __shared__ __align__(16) u16 VT[3][32*VTS];
  __shared__ float qn[CHU];
  __shared__ int spos_l[CHU];

  const int t = threadIdx.x;
  const int k = blockIdx.x, h = blockIdx.y;

  if (t < CHU){
    uint4 qv = *(const uint4*)(Qs + (size_t)(h*LTOT + k*CHU + t)*8);
    *(uint4*)(Qlds + t*8) = qv;
    float f0=bflo(qv.x), f1=bfhi(qv.x), f2=bflo(qv.y), f3=bfhi(qv.y);
    float f4=bflo(qv.z), f5=bfhi(qv.z), f6=bflo(qv.w), f7=bfhi(qv.w);
    qn[t] = sqrtf(f0*f0+f1*f1+f2*f2+f3*f3+f4*f4+f5*f5+f6*f6+f7*f7)*1.01f + 1e-6f;
    spos_l[t] = spos[h*LTOT + k*CHU + t];
    #pragma unroll
    for (int rr=0; rr<3; rr++){
      const int gkb = ((k + NCHUNK-1 + rr) & (NCHUNK-1)) * CHU;
      *(uint4*)(Klds + (rr*CHU + t)*8) =
          *(const uint4*)(Ks + (size_t)(h*LTOT + gkb + t)*8);
    }
  }
  for (int j = t; j < 432; j += 320){
    int p = j >> 1, hf = j & 1;
    int g = 2*p;
    int rg = g / CHU, lk = g - rg*CHU;
    const int gkb = ((k + NCHUNK-1 + rg) & (NCHUNK-1)) * CHU;
    const uint4* ra = (const uint4*)(Vs + (size_t)(h*LTOT + gkb + lk)*32);
    const uint4* rb = (const uint4*)(Vs + (size_t)(h*LTOT + gkb + lk+1)*32);
    uint4 A0 = ra[hf*2], A1 = ra[hf*2+1];
    uint4 B0 = rb[hf*2], B1 = rb[hf*2+1];
    u32 aw[8] = {A0.x,A0.y,A0.z,A0.w,A1.x,A1.y,A1.z,A1.w};
    u32 bw[8] = {B0.x,B0.y,B0.z,B0.w,B1.x,B1.y,B1.z,B1.w};
    int ebase = hf*16;
    u16* vtb = (u16*)VT[rg];
    #pragma unroll
    for (int m=0;m<8;m++){
      u32 al = aw[m]&0xffffu, ah = aw[m]>>16;
      u32 bl = bw[m]&0xffffu, bh = bw[m]>>16;
      *(u32*)&vtb[(ebase+2*m  )*VTS + lk] = al | (bl<<16);
      *(u32*)&vtb[(ebase+2*m+1)*VTS + lk] = ah | (bh<<16);
    }
  }
  __syncthreads();

  const int lane = t & 63;
  const int wv = t >> 6;                 // 0..4
  const int q = lane & 15;
  const int quad = lane >> 4;
  const bool two = (wv < 4);
  const int tl0 = 2*wv;
  const int tl1 = two ? (2*wv+1) : 8;

  const short4v zs = {0,0,0,0};
  short4v bq0 = zs, bq1 = zs;
  if (quad < 2){
    bq0 = *(const short4v*)(Qlds + (tl0*16+q)*8 + quad*4);
    if (two) bq1 = *(const short4v*)(Qlds + (tl1*16+q)*8 + quad*4);
  }
  const float m0 = qn[tl0*16+q];
  const float m1 = two ? qn[tl1*16+q] : 0.f;

  f32x4 o00={0,0,0,0}, o01={0,0,0,0}, o10={0,0,0,0}, o11={0,0,0,0};
  float s0 = 0.f, s1 = 0.f;

  #pragma unroll 3
  for (int kt=0; kt<27; kt++){
    const int rg = kt / 9, ktl = kt - rg*9;
    const u16* vtb = VT[rg];
    short4v av = zs;
    if (quad < 2) av = *(const short4v*)(Klds + (kt*16+q)*8 + quad*4);
    f32x4 zc = {0.f,0.f,0.f,0.f};
    f32x4 stA = __builtin_amdgcn_mfma_f32_16x16x16bf16_1k(av, bq0, zc, 0,0,0);

    float pA0 = __expf(stA[0]-m0), pA1 = __expf(stA[1]-m0);
    float pA2 = __expf(stA[2]-m0), pA3 = __expf(stA[3]-m0);
    s0 += (pA0+pA1)+(pA2+pA3);
    union { u32 u[2]; short4v s4; } pkA;
    pkA.u[0] = pkbf(pA0,pA1); pkA.u[1] = pkbf(pA2,pA3);

    short4v va0 = *(const short4v*)(&vtb[ q    *VTS + ktl*16 + quad*4]);
    short4v va1 = *(const short4v*)(&vtb[(q+16)*VTS + ktl*16 + quad*4]);
    o00 = __builtin_amdgcn_mfma_f32_16x16x16bf16_1k(va0, pkA.s4, o00, 0,0,0);
    o01 = __builtin_amdgcn_mfma_f32_16x16x16bf16_1k(va1, pkA.s4, o01, 0,0,0);

    if (two){
      f32x4 stB = __builtin_amdgcn_mfma_f32_16x16x16bf16_1k(av, bq1, zc, 0,0,0);
      float pB0 = __expf(stB[0]-m1), pB1 = __expf(stB[1]-m1);
      float pB2 = __expf(stB[2]-m1), pB3 = __expf(stB[3]-m1);
      s1 += (pB0+pB1)+(pB2+pB3);
      union { u32 u[2]; short4v s4; } pkB;
      pkB.u[0] = pkbf(pB0,pB1); pkB.u[1] = pkbf(pB2,pB3);
      o10 = __builtin_amdgcn_mfma_f32_16x16x16bf16_1k(va0, pkB.s4, o10, 0,0,0);
      o11 = __builtin_amdgcn_mfma_f32_16x16x16bf16_1k(va1, pkB.s4, o11, 0,0,0);
    }
  }

  float st0 = s0;
  st0 += __shfl_xor(st0, 16); st0 += __shfl_xor(st0, 32);
  float inv0 = 1.0f/st0;

  const int pos0 = spos_l[tl0*16 + q];
  u16* rp0 = ret_u + (size_t)(h*LTOT + pos0)*32;
  uint2 wA, wB;
  wA.x = pkbf(o00[0]*inv0, o00[1]*inv0); wA.y = pkbf(o00[2]*inv0, o00[3]*inv0);
  wB.x = pkbf(o01[0]*inv0, o01[1]*inv0); wB.y = pkbf(o01[2]*inv0, o01[3]*inv0);
  *(uint2*)&rp0[quad*4]    = wA;
  *(uint2*)&rp0[16+quad*4] = wB;
  if (quad == 0) bs_u[h*LTOT + pos0] = m0 + __logf(st0);

  if (two){
    float st1 = s1;
    st1 += __shfl_xor(st1, 16); st1 += __shfl_xor(st1, 32);
    float inv1 = 1.0f/st1;
    const int pos1 = spos_l[tl1*16 + q];
    u16* rp1 = ret_u + (size_t)(h*LTOT + pos1)*32;
    wA.x = pkbf(o10[0]*inv1, o10[1]*inv1); wA.y = pkbf(o10[2]*inv1, o10[3]*inv1);
    wB.x = pkbf(o11[0]*inv1, o11[1]*inv1); wB.y = pkbf(o11[2]*inv1, o11[3]*inv1);
    *(uint2*)&rp1[quad*4]    = wA;
    *(uint2*)&rp1[16+quad*4] = wB;
    if (quad == 0) bs_u[h*LTOT + pos1] = m1 + __logf(st1);
  }
}

// ---------------- cross-hash softmax + residual — fully coalesced ----------------
__global__ __launch_bounds__(256) void k_final(const float* __restrict__ x,
    const u16* __restrict__ ret_u, const float* __restrict__ bs_u,
    float* __restrict__ out)
{
  const int l  = blockIdx.x*64 + (threadIdx.x & 63);
  const int eg = threadIdx.x >> 6;
  float bs[NH];
  #pragma unroll
  for (int h=0;h<NH;h++) bs[h] = bs_u[h*LTOT + l];
  float m = fmaxf(fmaxf(bs[0],bs[1]), fmaxf(bs[2],bs[3]));
  float p[NH]; float s = 0.f;
  #pragma unroll
  for (int h=0;h<NH;h++){ p[h] = __expf(bs[h]-m); s += p[h]; }
  float inv = 1.0f/s;
  float o[8];
  #pragma unroll
  for (int e=0;e<8;e++) o[e]=0.f;
  #pragma unroll
  for (int h=0;h<NH;h++){
    float w = p[h]*inv;
    uint4 v = *(const uint4*)(ret_u + (size_t)(h*LTOT + l)*32 + eg*8);
    o[0] += w*bflo(v.x); o[1] += w*bfhi(v.x);
    o[2] += w*bflo(v.y); o[3] += w*bfhi(v.y);
    o[4] += w*bflo(v.z); o[5] += w*bfhi(v.z);
    o[6] += w*bflo(v.w); o[7] += w*bfhi(v.w);
  }
  #pragma unroll
  for (int e=0;e<8;e++){
    int ge = eg*8 + e;
    out[ge*LTOT + l] = o[e] + x[ge*LTOT + l];
  }
}

extern "C" void kernel_launch(void* const* d_in, const int* in_sizes, int n_in,
                              void* d_out, int out_size, void* d_ws, size_t ws_size,
                              hipStream_t stream)
{
  const float* x   = (const float*)d_in[0];
  const float* wm  = (const float*)d_in[1];
  const float* bm  = (const float*)d_in[2];
  const float* wa  = (const float*)d_in[3];
  const float* ba  = (const float*)d_in[4];
  const float* rot = (const float*)d_in[5];
  float* out = (float*)d_out;

  char* ws = (char*)d_ws;
  size_t off = 0;
  auto alloc = [&](size_t bytes)->void*{
    void* p = ws + off;
    off = (off + bytes + 255) & ~(size_t)255;
    return p;
  };
  float* xe     = (float*)alloc((size_t)LTOT*8*4);
  u16*   Vu     = (u16*)  alloc((size_t)LTOT*32*2);
  int*   code   = (int*)  alloc((size_t)NH*LTOT*4);
  int*   hist   = (int*)  alloc((size_t)NH*NSEG*NBUCK*4);
  int*   spos   = (int*)  alloc((size_t)NH*LTOT*4);
  u16*   Ks     = (u16*)  alloc((size_t)NH*LTOT*8*2);
  u16*   Qs     = (u16*)  alloc((size_t)NH*LTOT*8*2);
  u16*   Vs     = (u16*)  alloc((size_t)NH*LTOT*32*2);
  u16*   ret_u  = (u16*)  alloc((size_t)NH*LTOT*32*2);
  float* bs_u   = (float*)alloc((size_t)NH*LTOT*4);

  hipMemsetAsync(hist, 0, (size_t)NH*NSEG*NBUCK*4, stream);
  hipLaunchKernelGGL(k_conv,    dim3(576),        dim3(512), 0, stream, x, wm, bm, wa, ba, rot, xe, Vu, code, hist);
  hipLaunchKernelGGL(k_scatter, dim3(NSEG,NH),    dim3(256), 0, stream, code, hist, xe, Vu, spos, Ks, Qs, Vs);
  hipLaunchKernelGGL(k_attn,    dim3(NCHUNK,NH),  dim3(320), 0, stream, Ks, Qs, Vs, spos, ret_u, bs_u);
  hipLaunchKernelGGL(k_final,   dim3(576),        dim3(256), 0, stream, x, ret_u, bs_u, out);
}

// Round 14
// 125.816 us; speedup vs baseline: 1.0684x; 1.0684x over previous
//
#include <hip/hip_runtime.h>
#include <hip/hip_bf16.h>
#include <math.h>

#define LTOT 36864      // 192*192
#define NH 4
#define NCHUNK 256
#define CHU 144
#define NBUCK 128
#define NSEG 144        // 36864 / 256
#define HW_ 192
#define VTS 148         // VT row stride (u16)

typedef unsigned int u32;
typedef unsigned short u16;
typedef unsigned long long u64;
typedef __attribute__((ext_vector_type(4))) short short4v;
typedef __attribute__((ext_vector_type(4))) float f32x4;

__device__ __forceinline__ u32 pkbf(float a, float b){
  union { __hip_bfloat162 h2; u32 u; } cv;
  cv.h2 = __float22bfloat162_rn(float2{a,b});
  return cv.u;
}
__device__ __forceinline__ float bflo(u32 w){ return __uint_as_float(w<<16); }
__device__ __forceinline__ float bfhi(u32 w){ return __uint_as_float(w & 0xffff0000u); }

// ---------------- conv + hash + hist + bf16 K/Q/V pack (all unsorted): 576 blocks ----------------
// Wave w: 3x3 co-pair {2w,2w+1} + 1x1 co 8w..8w+7. Phase B: hash (px=lane,h=w);
// t<64 also packs Ku (normalized) / Qu (raw) bf16 rows from LDS xe rows.
__global__ __launch_bounds__(256) void k_conv(const float* __restrict__ x,
    const float* __restrict__ wm, const float* __restrict__ bm,
    const float* __restrict__ wa, const float* __restrict__ ba,
    const float* __restrict__ rot,
    u16* __restrict__ Ku, u16* __restrict__ Qu, u16* __restrict__ Vu,
    int* __restrict__ code, int* __restrict__ hist)
{
  __shared__ float xs[32*108];   // 32 ci x 6x18 halo
  __shared__ float xq[64*8];     // this tile's xe rows
  const int t = threadIdx.x;
  const int id = blockIdx.x;
  const int bx = id % 12, by = id / 12;

  for (int idx=t; idx<3456; idx+=256){
    int ci = idx/108, rem = idx-ci*108;
    int iy = rem/18,  ix = rem-iy*18;
    int yy = by*4+iy-1, xx = bx*16+ix-1;
    float v = 0.f;
    if (yy>=0 && yy<HW_ && xx>=0 && xx<HW_) v = x[ci*LTOT + yy*HW_ + xx];
    xs[idx] = v;
  }
  __syncthreads();
  const int lane = t & 63;
  const int w  = __builtin_amdgcn_readfirstlane(t>>6);
  const int co0 = 2*w, cb = 8*w;
  const int ix = lane & 15, iy = lane >> 4;
  float a0 = bm[co0], a1 = bm[co0+1];
  float acc[8];
  #pragma unroll
  for (int co=0;co<8;co++) acc[co] = ba[cb+co];
  const float* xb  = xs + iy*18 + ix;
  const float* w0p = wm + co0*288;
  const float* w1p = w0p + 288;
  for (int ci=0; ci<32; ci++){
    const float* xp = xb + ci*108;
    float x00=xp[0],  x01=xp[1],  x02=xp[2];
    float x10=xp[18], x11=xp[19], x12=xp[20];
    float x20=xp[36], x21=xp[37], x22=xp[38];
    const float* w0 = w0p + ci*9;
    const float* w1 = w1p + ci*9;
    a0 += x00*w0[0]+x01*w0[1]+x02*w0[2]
        + x10*w0[3]+x11*w0[4]+x12*w0[5]
        + x20*w0[6]+x21*w0[7]+x22*w0[8];
    a1 += x00*w1[0]+x01*w1[1]+x02*w1[2]
        + x10*w1[3]+x11*w1[4]+x12*w1[5]
        + x20*w1[6]+x21*w1[7]+x22*w1[8];
    const float* wap = wa + cb*32 + ci;
    #pragma unroll
    for (int co=0;co<8;co++) acc[co] += x11 * wap[co*32];
  }
  const int l = (by*4+iy)*HW_ + bx*16+ix;
  *(float2*)(xq + lane*8 + co0) = float2{a0,a1};
  uint4 vv;
  vv.x = pkbf(acc[0],acc[1]); vv.y = pkbf(acc[2],acc[3]);
  vv.z = pkbf(acc[4],acc[5]); vv.w = pkbf(acc[6],acc[7]);
  *(uint4*)(Vu + (size_t)l*32 + cb) = vv;
  __syncthreads();

  // pack Ku/Qu rows (t<64: one pixel each)
  if (t < 64){
    const int ly = t >> 4, lx = t & 15;
    const int lp = (by*4+ly)*HW_ + bx*16+lx;
    const float4* qp = (const float4*)(xq + t*8);
    float4 a = qp[0], b = qp[1];
    float n2 = a.x*a.x+a.y*a.y+a.z*a.z+a.w*a.w
             + b.x*b.x+b.y*b.y+b.z*b.z+b.w*b.w;
    float sc = 1.0f / fmaxf(sqrtf(n2), 5e-5f);
    uint4 kk, qq;
    kk.x = pkbf(a.x*sc,a.y*sc); kk.y = pkbf(a.z*sc,a.w*sc);
    kk.z = pkbf(b.x*sc,b.y*sc); kk.w = pkbf(b.z*sc,b.w*sc);
    qq.x = pkbf(a.x,a.y); qq.y = pkbf(a.z,a.w);
    qq.z = pkbf(b.x,b.y); qq.w = pkbf(b.z,b.w);
    *(uint4*)(Ku + (size_t)lp*8) = kk;
    *(uint4*)(Qu + (size_t)lp*8) = qq;
  }

  // hash: px = lane, h = wave id (wave-uniform rot access)
  {
    const int h = w;
    const float4* qp = (const float4*)(xq + lane*8);
    float4 qa = qp[0], qb = qp[1];
    float best = -INFINITY; int bi = 0;
    float worst = INFINITY; int wi = 0;
    for (int i=0; i<64; i++){
      const float* rp = rot + h*64 + i;   // rot[f*256 + h*64 + i]
      float v = qa.x*rp[0]    + qa.y*rp[256]  + qa.z*rp[512]  + qa.w*rp[768]
              + qb.x*rp[1024] + qb.y*rp[1280] + qb.z*rp[1536] + qb.w*rp[1792];
      if (v > best)  { best  = v; bi = i; }
      if (v < worst) { worst = v; wi = i; }
    }
    int c = (-worst > best) ? (64+wi) : bi;
    const int ly = lane >> 4, lx = lane & 15;
    const int lpix = (by*4+ly)*HW_ + bx*16+lx;
    code[h*LTOT + lpix] = c;
    atomicAdd(&hist[(h*NSEG + (lpix>>8))*NBUCK + c], 1);
  }
}

// ---------------- spos: per-block scan (from hist) + ballot rank ----------------
__global__ __launch_bounds__(256) void k_spos(const int* __restrict__ code,
    const int* __restrict__ hist, int* __restrict__ spos)
{
  const int h = blockIdx.y, seg = blockIdx.x, t = threadIdx.x;
  const int l = seg*256 + t;
  int c = code[h*LTOT + l];

  __shared__ int pre2[2][NBUCK], tot2[2][NBUCK];
  __shared__ int scv[NBUCK];
  __shared__ int segbase[NBUCK];
  __shared__ int wh[4][NBUCK];

  {
    const int b = t & 127, gg = t >> 7;
    int pre = 0, tt = 0;
    const int sA = gg*72;
    for (int s = sA; s < sA+72; s++){
      int v = hist[(h*NSEG+s)*NBUCK + b];
      tt += v;
      if (s < seg) pre += v;
    }
    pre2[gg][b] = pre; tot2[gg][b] = tt;
  }
  const int lane = t & 63, w = t >> 6;
  u64 mask = ~0ull;
  #pragma unroll
  for (int bit=0; bit<7; bit++){
    u64 bset = __ballot((c>>bit)&1);
    mask &= ((c>>bit)&1) ? bset : ~bset;
  }
  int rin = __popcll(mask & ((lane==0)?0ull:(~0ull >> (64-lane))));
  int cnt = __popcll(mask);
  ((int*)wh)[t] = 0; ((int*)wh)[t+256] = 0;
  __syncthreads();

  if (rin == 0) wh[w][c] = cnt;
  if (t < NBUCK){
    int tt = tot2[0][t] + tot2[1][t];
    int v = tt;
    #pragma unroll
    for (int off=1; off<64; off<<=1){
      int u = __shfl_up(v, off);
      if ((t & 63) >= off) v += u;
    }
    scv[t] = v;
  }
  __syncthreads();

  if (t < NBUCK){
    int tt = tot2[0][t] + tot2[1][t];
    int excl = scv[t] - tt + ((t >= 64) ? scv[63] : 0);
    segbase[t] = excl + pre2[0][t] + pre2[1][t];
  }
  __syncthreads();

  int r = segbase[c] + rin;
  for (int ww=0; ww<w; ww++) r += wh[ww][c];
  spos[h*LTOT + r] = l;
}

// ---------------- chunked attention: gather-staged via spos from shared unsorted Ku/Qu/Vu ----------------
__global__ __launch_bounds__(320) void k_attn(const u16* __restrict__ Ku,
    const u16* __restrict__ Qu, const u16* __restrict__ Vu,
    const int* __restrict__ spos, u16* __restrict__ ret_u, float* __restrict__ bs_u)
{
  __shared__ __align__(16) u16 Klds[432*8];
  __shared__ __align__(16) u16 Qlds[CHU*8];
  __shared__ __align__(16) u16 VT[3][32*VTS];
  __shared__ float qn[CHU];
  __shared__ int spos_l[CHU];

  const int t = threadIdx.x;
  const int k = blockIdx.x, h = blockIdx.y;

  if (t < CHU){
    int pos0 = spos[h*LTOT + k*CHU + t];
    spos_l[t] = pos0;
    uint4 qv = *(const uint4*)(Qu + (size_t)pos0*8);
    *(uint4*)(Qlds + t*8) = qv;
    float f0=bflo(qv.x), f1=bfhi(qv.x), f2=bflo(qv.y), f3=bfhi(qv.y);
    float f4=bflo(qv.z), f5=bfhi(qv.z), f6=bflo(qv.w), f7=bfhi(qv.w);
    qn[t] = sqrtf(f0*f0+f1*f1+f2*f2+f3*f3+f4*f4+f5*f5+f6*f6+f7*f7)*1.01f + 1e-6f;
    #pragma unroll
    for (int rr=0; rr<3; rr++){
      const int gkb = ((k + NCHUNK-1 + rr) & (NCHUNK-1)) * CHU;
      int pk = spos[h*LTOT + gkb + t];
      *(uint4*)(Klds + (rr*CHU + t)*8) = *(const uint4*)(Ku + (size_t)pk*8);
    }
  }
  for (int j = t; j < 432; j += 320){
    int p = j >> 1, hf = j & 1;
    int g = 2*p;
    int rg = g / CHU, lk = g - rg*CHU;
    const int gkb = ((k + NCHUNK-1 + rg) & (NCHUNK-1)) * CHU;
    int posA = spos[h*LTOT + gkb + lk];
    int posB = spos[h*LTOT + gkb + lk + 1];
    const uint4* ra = (const uint4*)(Vu + (size_t)posA*32);
    const uint4* rb = (const uint4*)(Vu + (size_t)posB*32);
    uint4 A0 = ra[hf*2], A1 = ra[hf*2+1];
    uint4 B0 = rb[hf*2], B1 = rb[hf*2+1];
    u32 aw[8] = {A0.x,A0.y,A0.z,A0.w,A1.x,A1.y,A1.z,A1.w};
    u32 bw[8] = {B0.x,B0.y,B0.z,B0.w,B1.x,B1.y,B1.z,B1.w};
    int ebase = hf*16;
    u16* vtb = (u16*)VT[rg];
    #pragma unroll
    for (int m=0;m<8;m++){
      u32 al = aw[m]&0xffffu, ah = aw[m]>>16;
      u32 bl = bw[m]&0xffffu, bh = bw[m]>>16;
      *(u32*)&vtb[(ebase+2*m  )*VTS + lk] = al | (bl<<16);
      *(u32*)&vtb[(ebase+2*m+1)*VTS + lk] = ah | (bh<<16);
    }
  }
  __syncthreads();

  const int lane = t & 63;
  const int wv = t >> 6;                 // 0..4
  const int q = lane & 15;
  const int quad = lane >> 4;
  const bool two = (wv < 4);
  const int tl0 = 2*wv;
  const int tl1 = two ? (2*wv+1) : 8;

  const short4v zs = {0,0,0,0};
  short4v bq0 = zs, bq1 = zs;
  if (quad < 2){
    bq0 = *(const short4v*)(Qlds + (tl0*16+q)*8 + quad*4);
    if (two) bq1 = *(const short4v*)(Qlds + (tl1*16+q)*8 + quad*4);
  }
  const float m0 = qn[tl0*16+q];
  const float m1 = two ? qn[tl1*16+q] : 0.f;

  f32x4 o00={0,0,0,0}, o01={0,0,0,0}, o10={0,0,0,0}, o11={0,0,0,0};
  float s0 = 0.f, s1 = 0.f;

  #pragma unroll 3
  for (int kt=0; kt<27; kt++){
    const int rg = kt / 9, ktl = kt - rg*9;
    const u16* vtb = VT[rg];
    short4v av = zs;
    if (quad < 2) av = *(const short4v*)(Klds + (kt*16+q)*8 + quad*4);
    f32x4 zc = {0.f,0.f,0.f,0.f};
    f32x4 stA = __builtin_amdgcn_mfma_f32_16x16x16bf16_1k(av, bq0, zc, 0,0,0);

    float pA0 = __expf(stA[0]-m0), pA1 = __expf(stA[1]-m0);
    float pA2 = __expf(stA[2]-m0), pA3 = __expf(stA[3]-m0);
    s0 += (pA0+pA1)+(pA2+pA3);
    union { u32 u[2]; short4v s4; } pkA;
    pkA.u[0] = pkbf(pA0,pA1); pkA.u[1] = pkbf(pA2,pA3);

    short4v va0 = *(const short4v*)(&vtb[ q    *VTS + ktl*16 + quad*4]);
    short4v va1 = *(const short4v*)(&vtb[(q+16)*VTS + ktl*16 + quad*4]);
    o00 = __builtin_amdgcn_mfma_f32_16x16x16bf16_1k(va0, pkA.s4, o00, 0,0,0);
    o01 = __builtin_amdgcn_mfma_f32_16x16x16bf16_1k(va1, pkA.s4, o01, 0,0,0);

    if (two){
      f32x4 stB = __builtin_amdgcn_mfma_f32_16x16x16bf16_1k(av, bq1, zc, 0,0,0);
      float pB0 = __expf(stB[0]-m1), pB1 = __expf(stB[1]-m1);
      float pB2 = __expf(stB[2]-m1), pB3 = __expf(stB[3]-m1);
      s1 += (pB0+pB1)+(pB2+pB3);
      union { u32 u[2]; short4v s4; } pkB;
      pkB.u[0] = pkbf(pB0,pB1); pkB.u[1] = pkbf(pB2,pB3);
      o10 = __builtin_amdgcn_mfma_f32_16x16x16bf16_1k(va0, pkB.s4, o10, 0,0,0);
      o11 = __builtin_amdgcn_mfma_f32_16x16x16bf16_1k(va1, pkB.s4, o11, 0,0,0);
    }
  }

  float st0 = s0;
  st0 += __shfl_xor(st0, 16); st0 += __shfl_xor(st0, 32);
  float inv0 = 1.0f/st0;

  const int pos0 = spos_l[tl0*16 + q];
  u16* rp0 = ret_u + (size_t)(h*LTOT + pos0)*32;
  uint2 wA, wB;
  wA.x = pkbf(o00[0]*inv0, o00[1]*inv0); wA.y = pkbf(o00[2]*inv0, o00[3]*inv0);
  wB.x = pkbf(o01[0]*inv0, o01[1]*inv0); wB.y = pkbf(o01[2]*inv0, o01[3]*inv0);
  *(uint2*)&rp0[quad*4]    = wA;
  *(uint2*)&rp0[16+quad*4] = wB;
  if (quad == 0) bs_u[h*LTOT + pos0] = m0 + __logf(st0);

  if (two){
    float st1 = s1;
    st1 += __shfl_xor(st1, 16); st1 += __shfl_xor(st1, 32);
    float inv1 = 1.0f/st1;
    const int pos1 = spos_l[tl1*16 + q];
    u16* rp1 = ret_u + (size_t)(h*LTOT + pos1)*32;
    wA.x = pkbf(o10[0]*inv1, o10[1]*inv1); wA.y = pkbf(o10[2]*inv1, o10[3]*inv1);
    wB.x = pkbf(o11[0]*inv1, o11[1]*inv1); wB.y = pkbf(o11[2]*inv1, o11[3]*inv1);
    *(uint2*)&rp1[quad*4]    = wA;
    *(uint2*)&rp1[16+quad*4] = wB;
    if (quad == 0) bs_u[h*LTOT + pos1] = m1 + __logf(st1);
  }
}

// ---------------- cross-hash softmax + residual — fully coalesced ----------------
__global__ __launch_bounds__(256) void k_final(const float* __restrict__ x,
    const u16* __restrict__ ret_u, const float* __restrict__ bs_u,
    float* __restrict__ out)
{
  const int l  = blockIdx.x*64 + (threadIdx.x & 63);
  const int eg = threadIdx.x >> 6;
  float bs[NH];
  #pragma unroll
  for (int h=0;h<NH;h++) bs[h] = bs_u[h*LTOT + l];
  float m = fmaxf(fmaxf(bs[0],bs[1]), fmaxf(bs[2],bs[3]));
  float p[NH]; float s = 0.f;
  #pragma unroll
  for (int h=0;h<NH;h++){ p[h] = __expf(bs[h]-m); s += p[h]; }
  float inv = 1.0f/s;
  float o[8];
  #pragma unroll
  for (int e=0;e<8;e++) o[e]=0.f;
  #pragma unroll
  for (int h=0;h<NH;h++){
    float w = p[h]*inv;
    uint4 v = *(const uint4*)(ret_u + (size_t)(h*LTOT + l)*32 + eg*8);
    o[0] += w*bflo(v.x); o[1] += w*bfhi(v.x);
    o[2] += w*bflo(v.y); o[3] += w*bfhi(v.y);
    o[4] += w*bflo(v.z); o[5] += w*bfhi(v.z);
    o[6] += w*bflo(v.w); o[7] += w*bfhi(v.w);
  }
  #pragma unroll
  for (int e=0;e<8;e++){
    int ge = eg*8 + e;
    out[ge*LTOT + l] = o[e] + x[ge*LTOT + l];
  }
}

extern "C" void kernel_launch(void* const* d_in, const int* in_sizes, int n_in,
                              void* d_out, int out_size, void* d_ws, size_t ws_size,
                              hipStream_t stream)
{
  const float* x   = (const float*)d_in[0];
  const float* wm  = (const float*)d_in[1];
  const float* bm  = (const float*)d_in[2];
  const float* wa  = (const float*)d_in[3];
  const float* ba  = (const float*)d_in[4];
  const float* rot = (const float*)d_in[5];
  float* out = (float*)d_out;

  char* ws = (char*)d_ws;
  size_t off = 0;
  auto alloc = [&](size_t bytes)->void*{
    void* p = ws + off;
    off = (off + bytes + 255) & ~(size_t)255;
    return p;
  };
  u16*   Ku     = (u16*)  alloc((size_t)LTOT*8*2);
  u16*   Qu     = (u16*)  alloc((size_t)LTOT*8*2);
  u16*   Vu     = (u16*)  alloc((size_t)LTOT*32*2);
  int*   code   = (int*)  alloc((size_t)NH*LTOT*4);
  int*   hist   = (int*)  alloc((size_t)NH*NSEG*NBUCK*4);
  int*   spos   = (int*)  alloc((size_t)NH*LTOT*4);
  u16*   ret_u  = (u16*)  alloc((size_t)NH*LTOT*32*2);
  float* bs_u   = (float*)alloc((size_t)NH*LTOT*4);

  hipMemsetAsync(hist, 0, (size_t)NH*NSEG*NBUCK*4, stream);
  hipLaunchKernelGGL(k_conv,   dim3(576),        dim3(256), 0, stream, x, wm, bm, wa, ba, rot, Ku, Qu, Vu, code, hist);
  hipLaunchKernelGGL(k_spos,   dim3(NSEG,NH),    dim3(256), 0, stream, code, hist, spos);
  hipLaunchKernelGGL(k_attn,   dim3(NCHUNK,NH),  dim3(320), 0, stream, Ku, Qu, Vu, spos, ret_u, bs_u);
  hipLaunchKernelGGL(k_final,  dim3(576),        dim3(256), 0, stream, x, ret_u, bs_u, out);
}